// Round 11
// baseline (356.995 us; speedup 1.0000x reference)
//
#include <hip/hip_runtime.h>
#include <hip/hip_bf16.h>

typedef __attribute__((ext_vector_type(8))) __bf16 bf16x8;
typedef __attribute__((ext_vector_type(4))) float f32x4;

#define DEVI static __device__ __forceinline__

// ---- helpers ---------------------------------------------------------------

DEVI ushort f2bf(float f) {
  unsigned u = __builtin_bit_cast(unsigned, f);
  return (ushort)((u + 0x7fffu + ((u >> 16) & 1u)) >> 16);
}

union BF8 { unsigned u[4]; bf16x8 v; };

DEVI bf16x8 cvt8(const float* __restrict__ p) {
  const f32x4 a = *(const f32x4*)p;
  const f32x4 b = *(const f32x4*)(p + 4);
  BF8 r;
  asm("v_cvt_pk_bf16_f32 %0, %1, %2" : "=v"(r.u[0]) : "v"(a.x), "v"(a.y));
  asm("v_cvt_pk_bf16_f32 %0, %1, %2" : "=v"(r.u[1]) : "v"(a.z), "v"(a.w));
  asm("v_cvt_pk_bf16_f32 %0, %1, %2" : "=v"(r.u[2]) : "v"(b.x), "v"(b.y));
  asm("v_cvt_pk_bf16_f32 %0, %1, %2" : "=v"(r.u[3]) : "v"(b.z), "v"(b.w));
  return r.v;
}

DEVI void gload16(const void* g, void* l) {
  __builtin_amdgcn_global_load_lds(
      (const __attribute__((address_space(1))) unsigned*)g,
      (__attribute__((address_space(3))) unsigned*)l, 16, 0, 0);
}

DEVI int xcd_swizzle(int bid, int nwg) {
  return (bid & 7) * (nwg >> 3) + (bid >> 3);
}

// ---- converts (nontemporal stores: don't evict L3-resident inputs) ---------

__global__ __launch_bounds__(256) void cvt_qkv(
    const float* __restrict__ q, const float* __restrict__ k,
    const float* __restrict__ v, ushort* __restrict__ oq,
    ushort* __restrict__ ok2, ushort* __restrict__ ov) {
  const int s = blockIdx.x >> 11;          // 0..2 (uniform per block)
  const int tb = blockIdx.x & 2047;
  const float* src = s == 0 ? q : (s == 1 ? k : v);
  ushort* dst = s == 0 ? oq : (s == 1 ? ok2 : ov);
  const unsigned G = 2048 * 256;
  const unsigned t = tb * 256 + threadIdx.x;
#pragma unroll
  for (int j = 0; j < 4; ++j) {
    const size_t i = (size_t)t + (size_t)j * G;
    __builtin_nontemporal_store(cvt8(src + i * 8), (bf16x8*)(dst + i * 8));
  }
}

__global__ __launch_bounds__(256) void cvt_w(
    const float* __restrict__ wq, const float* __restrict__ wk,
    const float* __restrict__ wv, const float* __restrict__ wo,
    ushort* __restrict__ oq, ushort* __restrict__ ok2,
    ushort* __restrict__ ov, ushort* __restrict__ oo) {
  const int s = blockIdx.x >> 7;           // 0..3
  const int tb = blockIdx.x & 127;
  const float* src = s == 0 ? wq : (s == 1 ? wk : (s == 2 ? wv : wo));
  ushort* dst = s == 0 ? oq : (s == 1 ? ok2 : (s == 2 ? ov : oo));
  const unsigned G = 128 * 256;
  const unsigned t = tb * 256 + threadIdx.x;
#pragma unroll
  for (int j = 0; j < 4; ++j) {
    const size_t i = (size_t)t + (size_t)j * G;
    *(bf16x8*)(dst + i * 8) = cvt8(src + i * 8);
  }
}

// ---- GEMM: BM=BN=256, BK=32, 512 threads (8 waves 2Mx4N), depth-4 LDS ------
// Per-wave output 128x64 (8x4 acc, 128 VGPR). Tile t+3 staged during iter t
// into buf (t+3)&3 -> loads are ~3 K-tiles old at consumption; vmcnt(8) only,
// never 0, in the main loop. ONE barrier per K-tile (entry): WAR safe since
// buf (t+3)&3 was last read in iter t-1 and all waves passed t's entry
// barrier. LDS layout: 128B lines = 2 logical rows, 8x16B slots, XOR swizzle
// slot=(4*(r&1)+ku)^((r>>1)&7) -> column-slice ds_read_b128 is 2-way (free);
// staged linearly via pre-swizzled global source (both-sides rule).

template <int OUT_BF16>
__global__ __launch_bounds__(512, 2) void gemm_d4(
    const ushort* __restrict__ A, const ushort* __restrict__ B,
    const float* __restrict__ bias, void* __restrict__ Cp, int N, int K) {
  __shared__ __align__(16) ushort Asm[4][8192];  // 4 x 16 KB
  __shared__ __align__(16) ushort Bsm[4][8192];  // 4 x 16 KB
  const int tid = threadIdx.x, lane = tid & 63;
  const int wv = tid >> 6;
  const int wr = wv >> 2, wc = wv & 3;       // 2 M-waves x 4 N-waves
  const int cc = lane & 15, cr = lane >> 4;
  const int nw = N >> 8;                     // 256-col tiles
  const int work = xcd_swizzle(blockIdx.x, gridDim.x);
  const size_t m0 = (size_t)(work / nw) * 256;
  const size_t n0 = (size_t)(work % nw) * 256;

  // staging: 1024 16B units per operand per K-tile; thread covers units
  // tid and tid+512. Unit u -> LDS linear u*16B; global source unswizzled:
  // lrow=u>>3, slot=u&7, y=slot^(lrow&7), r=2*lrow+(y>>2), ku=y&3.
  const ushort *agp[2], *bgp[2];
  const int uu[2] = {tid, tid + 512};
#pragma unroll
  for (int i = 0; i < 2; ++i) {
    const int u = uu[i], lrow = u >> 3, slot = u & 7;
    const int y = slot ^ (lrow & 7);
    const int r = lrow * 2 + (y >> 2), ku = y & 3;
    agp[i] = A + (m0 + r) * (size_t)K + ku * 8;
    bgp[i] = B + (n0 + r) * (size_t)K + ku * 8;
  }

  auto stage = [&](int buf, int kt) {
#pragma unroll
    for (int i = 0; i < 2; ++i) {
      gload16(agp[i] + kt, &Asm[buf][uu[i] * 8]);
      gload16(bgp[i] + kt, &Bsm[buf][uu[i] * 8]);
    }
  };

  f32x4 acc[8][4] = {};
  const int nt = K >> 5;  // 32

  stage(0, 0);
  stage(1, 32);
  stage(2, 64);

  for (int t = 0; t < nt; ++t) {
    if (t + 2 < nt) {
      asm volatile("s_waitcnt vmcnt(8)" ::: "memory");   // tile t landed
    } else if (t + 1 < nt) {
      asm volatile("s_waitcnt vmcnt(4)" ::: "memory");
    } else {
      asm volatile("s_waitcnt vmcnt(0)" ::: "memory");
    }
    __builtin_amdgcn_s_barrier();
    asm volatile("" ::: "memory");

    if (t + 3 < nt) stage((t + 3) & 3, (t + 3) << 5);

    const ushort* Ab = Asm[t & 3];
    const ushort* Bb = Bsm[t & 3];
    bf16x8 bfr[4];
#pragma unroll
    for (int n = 0; n < 4; ++n) {
      const int rr = wc * 64 + n * 16 + cc;
      const int lrow = rr >> 1;
      const int slot = ((rr & 1) * 4 + cr) ^ (lrow & 7);
      bfr[n] = *(const bf16x8*)&Bb[(lrow * 8 + slot) * 8];
    }
    bf16x8 af[8];
#pragma unroll
    for (int m = 0; m < 8; ++m) {
      const int rr = wr * 128 + m * 16 + cc;
      const int lrow = rr >> 1;
      const int slot = ((rr & 1) * 4 + cr) ^ (lrow & 7);
      af[m] = *(const bf16x8*)&Ab[(lrow * 8 + slot) * 8];
    }
    __builtin_amdgcn_s_setprio(1);
#pragma unroll
    for (int m = 0; m < 8; ++m)
#pragma unroll
      for (int n = 0; n < 4; ++n)
        acc[m][n] =
            __builtin_amdgcn_mfma_f32_16x16x32_bf16(af[m], bfr[n], acc[m][n], 0, 0, 0);
    __builtin_amdgcn_s_setprio(0);
    asm volatile("" ::: "memory");
  }

  // epilogue
#pragma unroll
  for (int n = 0; n < 4; ++n) {
    const size_t col = n0 + wc * 64 + n * 16 + cc;
    const float bval = bias[col];
#pragma unroll
    for (int m = 0; m < 8; ++m) {
      const size_t row0 = m0 + wr * 128 + m * 16 + cr * 4;
#pragma unroll
      for (int r = 0; r < 4; ++r) {
        const float val = acc[m][n][r] + bval;
        if constexpr (OUT_BF16)
          ((ushort*)Cp)[(row0 + r) * N + col] = f2bf(val);
        else
          ((float*)Cp)[(row0 + r) * N + col] = val;
      }
    }
  }
}

// ---- windowed attention ----------------------------------------------------
// grid = B*H*NW = 1024 blocks, 256 threads (4 waves x 64 q-rows).
// q/k/v: bf16 [B*S, D] with col = h*64+dk. Output written in-place over q.

__global__ __launch_bounds__(256) void attn_kernel(
    const ushort* __restrict__ q, const ushort* __restrict__ k,
    const ushort* __restrict__ v, ushort* __restrict__ x) {
  __shared__ ushort Ks[256 * 72];
  __shared__ ushort Vt[64 * 264];
  __shared__ ushort Pw[4][16 * 264];
  const int bid = blockIdx.x;
  const int w = bid & 15, h = (bid >> 4) & 15, b = bid >> 8;
  const int tid = threadIdx.x, lane = tid & 63, wv = tid >> 6;
  const int cc = lane & 15, cr = lane >> 4;
  const size_t base = ((size_t)b * 4096 + (size_t)w * 256) * 1024 + h * 64;

#pragma unroll
  for (int i = 0; i < 8; ++i) {
    const int ch = i * 256 + tid;
    const int row = ch >> 3, kc = ch & 7;
    bf16x8 val = *(const bf16x8*)(k + base + (size_t)row * 1024 + kc * 8);
    *(bf16x8*)&Ks[row * 72 + kc * 8] = val;
  }
  {
    const ushort* vp = v + base + (size_t)tid * 1024;
#pragma unroll
    for (int j = 0; j < 8; ++j) {
      bf16x8 vvv = *(const bf16x8*)(vp + j * 8);
#pragma unroll
      for (int e = 0; e < 8; ++e)
        Vt[(j * 8 + e) * 264 + tid] = __builtin_bit_cast(ushort, (__bf16)vvv[e]);
    }
  }
  __syncthreads();

  ushort* Pp = Pw[wv];
  for (int c = 0; c < 4; ++c) {
    const int qrow0 = wv * 64 + c * 16;
    const ushort* qp = q + base + (size_t)(qrow0 + cc) * 1024 + cr * 8;
    const bf16x8 qf0 = *(const bf16x8*)qp;
    const bf16x8 qf1 = *(const bf16x8*)(qp + 32);

    f32x4 sc[16];
#pragma unroll
    for (int cb = 0; cb < 16; ++cb) {
      const bf16x8 kb0 = *(const bf16x8*)&Ks[(cb * 16 + cc) * 72 + cr * 8];
      const bf16x8 kb1 = *(const bf16x8*)&Ks[(cb * 16 + cc) * 72 + 32 + cr * 8];
      f32x4 z = {0.f, 0.f, 0.f, 0.f};
      z = __builtin_amdgcn_mfma_f32_16x16x32_bf16(qf0, kb0, z, 0, 0, 0);
      z = __builtin_amdgcn_mfma_f32_16x16x32_bf16(qf1, kb1, z, 0, 0, 0);
      sc[cb] = z;
    }

    float inv[4];
#pragma unroll
    for (int r = 0; r < 4; ++r) {
      float mx = -1e30f;
#pragma unroll
      for (int cb = 0; cb < 16; ++cb) mx = fmaxf(mx, sc[cb][r]);
      mx = fmaxf(mx, __shfl_xor(mx, 1));
      mx = fmaxf(mx, __shfl_xor(mx, 2));
      mx = fmaxf(mx, __shfl_xor(mx, 4));
      mx = fmaxf(mx, __shfl_xor(mx, 8));
      float sum = 0.f;
#pragma unroll
      for (int cb = 0; cb < 16; ++cb) {
        const float p = __expf((sc[cb][r] - mx) * 0.125f);
        sc[cb][r] = p;
        sum += p;
      }
      sum += __shfl_xor(sum, 1);
      sum += __shfl_xor(sum, 2);
      sum += __shfl_xor(sum, 4);
      sum += __shfl_xor(sum, 8);
      inv[r] = 1.f / sum;
    }

#pragma unroll
    for (int r = 0; r < 4; ++r)
#pragma unroll
      for (int cb = 0; cb < 16; ++cb)
        Pp[(cr * 4 + r) * 264 + cb * 16 + cc] = f2bf(sc[cb][r]);

    bf16x8 pf[8];
#pragma unroll
    for (int ks = 0; ks < 8; ++ks)
      pf[ks] = *(const bf16x8*)&Pp[cc * 264 + ks * 32 + cr * 8];
    f32x4 o[4] = {};
#pragma unroll
    for (int db = 0; db < 4; ++db)
#pragma unroll
      for (int ks = 0; ks < 8; ++ks) {
        const bf16x8 bv = *(const bf16x8*)&Vt[(db * 16 + cc) * 264 + ks * 32 + cr * 8];
        o[db] = __builtin_amdgcn_mfma_f32_16x16x32_bf16(pf[ks], bv, o[db], 0, 0, 0);
      }

#pragma unroll
    for (int db = 0; db < 4; ++db)
#pragma unroll
      for (int r = 0; r < 4; ++r) {
        const int qr = qrow0 + cr * 4 + r;
        x[base + (size_t)qr * 1024 + db * 16 + cc] = f2bf(o[db][r] * inv[r]);
      }
  }
}

// ---- launch ----------------------------------------------------------------

extern "C" void kernel_launch(void* const* d_in, const int* in_sizes, int n_in,
                              void* d_out, int out_size, void* d_ws, size_t ws_size,
                              hipStream_t stream) {
  const float* query = (const float*)d_in[0];
  const float* key_  = (const float*)d_in[1];
  const float* value = (const float*)d_in[2];
  const float* Wq = (const float*)d_in[3];
  const float* bq = (const float*)d_in[4];
  const float* Wk = (const float*)d_in[5];
  const float* bk = (const float*)d_in[6];
  const float* Wv = (const float*)d_in[7];
  const float* bv = (const float*)d_in[8];
  const float* Wo = (const float*)d_in[9];
  const float* bo = (const float*)d_in[10];
  float* out = (float*)d_out;

  const size_t MN = (size_t)16384 * 1024;
  const size_t WN = (size_t)1024 * 1024;
  ushort* qb = (ushort*)d_ws;
  ushort* kb = qb + MN;
  ushort* vb = kb + MN;
  ushort* wqb = vb + MN;
  ushort* wkb = wqb + WN;
  ushort* wvb = wkb + WN;
  ushort* wob = wvb + WN;
  ushort* qp = wob + WN;
  ushort* kp = qp + MN;
  ushort* vp = kp + MN;

  const dim3 b256(256), b512(512);
  const dim3 ggrid(64 * 4);  // (16384/256) * (1024/256) = 256 blocks

  cvt_qkv<<<dim3(3 * 2048), b256, 0, stream>>>(query, key_, value, qb, kb, vb);
  cvt_w<<<dim3(4 * 128), b256, 0, stream>>>(Wq, Wk, Wv, Wo, wqb, wkb, wvb, wob);

  gemm_d4<1><<<ggrid, b512, 0, stream>>>(qb, wqb, bq, qp, 1024, 1024);
  gemm_d4<1><<<ggrid, b512, 0, stream>>>(kb, wkb, bk, kp, 1024, 1024);
  gemm_d4<1><<<ggrid, b512, 0, stream>>>(vb, wvb, bv, vp, 1024, 1024);

  attn_kernel<<<dim3(1024), b256, 0, stream>>>(qp, kp, vp, qp /*in-place*/);

  gemm_d4<0><<<ggrid, b512, 0, stream>>>(qp, wob, bo, out, 1024, 1024);
}

// Round 12
// 321.567 us; speedup vs baseline: 1.1102x; 1.1102x over previous
//
#include <hip/hip_runtime.h>
#include <hip/hip_bf16.h>

typedef __attribute__((ext_vector_type(8))) __bf16 bf16x8;
typedef __attribute__((ext_vector_type(4))) float f32x4;

#define DEVI static __device__ __forceinline__

// ---- helpers ---------------------------------------------------------------

DEVI ushort f2bf(float f) {
  unsigned u = __builtin_bit_cast(unsigned, f);
  return (ushort)((u + 0x7fffu + ((u >> 16) & 1u)) >> 16);
}

union BF8 { unsigned u[4]; bf16x8 v; };

DEVI bf16x8 cvt8(const float* __restrict__ p) {
  const f32x4 a = *(const f32x4*)p;
  const f32x4 b = *(const f32x4*)(p + 4);
  BF8 r;
  asm("v_cvt_pk_bf16_f32 %0, %1, %2" : "=v"(r.u[0]) : "v"(a.x), "v"(a.y));
  asm("v_cvt_pk_bf16_f32 %0, %1, %2" : "=v"(r.u[1]) : "v"(a.z), "v"(a.w));
  asm("v_cvt_pk_bf16_f32 %0, %1, %2" : "=v"(r.u[2]) : "v"(b.x), "v"(b.y));
  asm("v_cvt_pk_bf16_f32 %0, %1, %2" : "=v"(r.u[3]) : "v"(b.z), "v"(b.w));
  return r.v;
}

DEVI bf16x8 cvt8r(f32x4 a, f32x4 b) {
  BF8 r;
  asm("v_cvt_pk_bf16_f32 %0, %1, %2" : "=v"(r.u[0]) : "v"(a.x), "v"(a.y));
  asm("v_cvt_pk_bf16_f32 %0, %1, %2" : "=v"(r.u[1]) : "v"(a.z), "v"(a.w));
  asm("v_cvt_pk_bf16_f32 %0, %1, %2" : "=v"(r.u[2]) : "v"(b.x), "v"(b.y));
  asm("v_cvt_pk_bf16_f32 %0, %1, %2" : "=v"(r.u[3]) : "v"(b.z), "v"(b.w));
  return r.v;
}

DEVI void gload16(const void* g, void* l) {
  __builtin_amdgcn_global_load_lds(
      (const __attribute__((address_space(1))) unsigned*)g,
      (__attribute__((address_space(3))) unsigned*)l, 16, 0, 0);
}

DEVI int xcd_swizzle(int bid, int nwg) {
  return (bid & 7) * (nwg >> 3) + (bid >> 3);
}

// ---- cvt_qkv: 8 chunks/thread, explicit ILP --------------------------------
// All 16 f32x4 loads issued back-to-back (NT: f32 source is dead after this),
// then convert + regular stores (bf16 output is re-read by the GEMMs -> keep
// it cacheable). 3 tensors x 1024 blocks; each block covers 2048 consecutive
// chunks of 8 elems (wave reads 2 KB contiguous per j-slice).

__global__ __launch_bounds__(256) void cvt_qkv(
    const float* __restrict__ q, const float* __restrict__ k,
    const float* __restrict__ v, ushort* __restrict__ oq,
    ushort* __restrict__ ok2, ushort* __restrict__ ov) {
  const int s = blockIdx.x >> 10;          // 0..2 (uniform per block)
  const int tb = blockIdx.x & 1023;
  const float* src = s == 0 ? q : (s == 1 ? k : v);
  ushort* dst = s == 0 ? oq : (s == 1 ? ok2 : ov);
  const size_t base = (size_t)tb * 2048 + threadIdx.x;

  f32x4 va[8], vb[8];
#pragma unroll
  for (int j = 0; j < 8; ++j) {
    const float* p = src + (base + j * 256) * 8;
    va[j] = __builtin_nontemporal_load((const f32x4*)p);
    vb[j] = __builtin_nontemporal_load((const f32x4*)(p + 4));
  }
#pragma unroll
  for (int j = 0; j < 8; ++j)
    *(bf16x8*)(dst + (base + j * 256) * 8) = cvt8r(va[j], vb[j]);
}

__global__ __launch_bounds__(256) void cvt_w(
    const float* __restrict__ wq, const float* __restrict__ wk,
    const float* __restrict__ wv, const float* __restrict__ wo,
    ushort* __restrict__ oq, ushort* __restrict__ ok2,
    ushort* __restrict__ ov, ushort* __restrict__ oo) {
  const int s = blockIdx.x >> 7;           // 0..3
  const int tb = blockIdx.x & 127;
  const float* src = s == 0 ? wq : (s == 1 ? wk : (s == 2 ? wv : wo));
  ushort* dst = s == 0 ? oq : (s == 1 ? ok2 : (s == 2 ? ov : oo));
  const unsigned G = 128 * 256;
  const unsigned t = tb * 256 + threadIdx.x;
#pragma unroll
  for (int j = 0; j < 4; ++j) {
    const size_t i = (size_t)t + (size_t)j * G;
    *(bf16x8*)(dst + i * 8) = cvt8(src + i * 8);
  }
}

// ---- GEMM (bf16 x bf16): C[M,N] = A @ W^T + bias ---------------------------
// 128x128 tile, BK=32, 256 threads (4 waves), 2-phase double-buffered LDS:
// STAGE(t+1) before computing tile t; counted vmcnt(4) + raw s_barrier keeps
// next-tile loads in flight under compute. 32 KB LDS -> 4-5 blocks/CU whose
// interleaved barriers hide per-block stalls (measured best: ~58 us at
// M=16384/N=1024/K=1024; both 256-tile deep-pipeline variants were worse).

template <int OUT_BF16>
__global__ __launch_bounds__(256) void gemm_2ph(
    const ushort* __restrict__ A, const ushort* __restrict__ B,
    const float* __restrict__ bias, void* __restrict__ Cp, int N, int K) {
  __shared__ __align__(16) ushort As[2][128 * 32];
  __shared__ __align__(16) ushort Bs[2][128 * 32];
  const int tid = threadIdx.x, lane = tid & 63;
  const int wv = tid >> 6, wr = wv >> 1, wc = wv & 1;
  const int cc = lane & 15, cr = lane >> 4;
  const int ntiles = N >> 7;
  const int work = xcd_swizzle(blockIdx.x, gridDim.x);
  const size_t m0 = (size_t)(work / ntiles) * 128;
  const size_t n0 = (size_t)(work % ntiles) * 128;

  const int ch0 = tid, ch1 = tid + 256;
  const int row0 = ch0 >> 2, u0 = ch0 & 3;
  const int row1 = ch1 >> 2, u1 = ch1 & 3;
  const int sw0 = (u0 ^ ((row0 >> 1) & 3)) * 8;
  const int sw1 = (u1 ^ ((row1 >> 1) & 3)) * 8;
  const ushort* a0 = A + (m0 + row0) * (size_t)K + sw0;
  const ushort* a1 = A + (m0 + row1) * (size_t)K + sw1;
  const ushort* b0 = B + (n0 + row0) * (size_t)K + sw0;
  const ushort* b1 = B + (n0 + row1) * (size_t)K + sw1;

  auto stage = [&](int bf, int kt) {
    gload16(a0 + kt, &As[bf][ch0 * 8]);
    gload16(a1 + kt, &As[bf][ch1 * 8]);
    gload16(b0 + kt, &Bs[bf][ch0 * 8]);
    gload16(b1 + kt, &Bs[bf][ch1 * 8]);
  };

  f32x4 acc[4][4] = {};
  const int nt = K >> 5;

  stage(0, 0);
  for (int t = 0; t < nt; ++t) {
    const int cur = t & 1;
    if (t + 1 < nt) {
      stage(cur ^ 1, (t + 1) << 5);
      asm volatile("s_waitcnt vmcnt(4)" ::: "memory");
    } else {
      asm volatile("s_waitcnt vmcnt(0)" ::: "memory");
    }
    __builtin_amdgcn_s_barrier();
    asm volatile("" ::: "memory");

    bf16x8 af[4], bfr[4];
#pragma unroll
    for (int m = 0; m < 4; ++m) {
      const int row = wr * 64 + m * 16 + cc;
      af[m] = *(const bf16x8*)&As[cur][row * 32 + (cr ^ ((row >> 1) & 3)) * 8];
    }
#pragma unroll
    for (int n = 0; n < 4; ++n) {
      const int row = wc * 64 + n * 16 + cc;
      bfr[n] = *(const bf16x8*)&Bs[cur][row * 32 + (cr ^ ((row >> 1) & 3)) * 8];
    }
#pragma unroll
    for (int m = 0; m < 4; ++m)
#pragma unroll
      for (int n = 0; n < 4; ++n)
        acc[m][n] =
            __builtin_amdgcn_mfma_f32_16x16x32_bf16(af[m], bfr[n], acc[m][n], 0, 0, 0);

    asm volatile("" ::: "memory");
    __builtin_amdgcn_s_barrier();
  }

#pragma unroll
  for (int n = 0; n < 4; ++n) {
    const size_t col = n0 + wc * 64 + n * 16 + cc;
    const float bval = bias[col];
#pragma unroll
    for (int m = 0; m < 4; ++m) {
      const size_t row0_ = m0 + wr * 64 + m * 16 + cr * 4;
#pragma unroll
      for (int r = 0; r < 4; ++r) {
        const float val = acc[m][n][r] + bval;
        if constexpr (OUT_BF16)
          ((ushort*)Cp)[(row0_ + r) * N + col] = f2bf(val);
        else
          ((float*)Cp)[(row0_ + r) * N + col] = val;
      }
    }
  }
}

// ---- windowed attention ----------------------------------------------------
// grid = B*H*NW = 1024 blocks, 256 threads (4 waves x 64 q-rows).
// q/k/v: bf16 [B*S, D] with col = h*64+dk. Output written in-place over q.

__global__ __launch_bounds__(256) void attn_kernel(
    const ushort* __restrict__ q, const ushort* __restrict__ k,
    const ushort* __restrict__ v, ushort* __restrict__ x) {
  __shared__ ushort Ks[256 * 72];
  __shared__ ushort Vt[64 * 264];
  __shared__ ushort Pw[4][16 * 264];
  const int bid = blockIdx.x;
  const int w = bid & 15, h = (bid >> 4) & 15, b = bid >> 8;
  const int tid = threadIdx.x, lane = tid & 63, wv = tid >> 6;
  const int cc = lane & 15, cr = lane >> 4;
  const size_t base = ((size_t)b * 4096 + (size_t)w * 256) * 1024 + h * 64;

#pragma unroll
  for (int i = 0; i < 8; ++i) {
    const int ch = i * 256 + tid;
    const int row = ch >> 3, kc = ch & 7;
    bf16x8 val = *(const bf16x8*)(k + base + (size_t)row * 1024 + kc * 8);
    *(bf16x8*)&Ks[row * 72 + kc * 8] = val;
  }
  {
    const ushort* vp = v + base + (size_t)tid * 1024;
#pragma unroll
    for (int j = 0; j < 8; ++j) {
      bf16x8 vvv = *(const bf16x8*)(vp + j * 8);
#pragma unroll
      for (int e = 0; e < 8; ++e)
        Vt[(j * 8 + e) * 264 + tid] = __builtin_bit_cast(ushort, (__bf16)vvv[e]);
    }
  }
  __syncthreads();

  ushort* Pp = Pw[wv];
  for (int c = 0; c < 4; ++c) {
    const int qrow0 = wv * 64 + c * 16;
    const ushort* qp = q + base + (size_t)(qrow0 + cc) * 1024 + cr * 8;
    const bf16x8 qf0 = *(const bf16x8*)qp;
    const bf16x8 qf1 = *(const bf16x8*)(qp + 32);

    f32x4 sc[16];
#pragma unroll
    for (int cb = 0; cb < 16; ++cb) {
      const bf16x8 kb0 = *(const bf16x8*)&Ks[(cb * 16 + cc) * 72 + cr * 8];
      const bf16x8 kb1 = *(const bf16x8*)&Ks[(cb * 16 + cc) * 72 + 32 + cr * 8];
      f32x4 z = {0.f, 0.f, 0.f, 0.f};
      z = __builtin_amdgcn_mfma_f32_16x16x32_bf16(qf0, kb0, z, 0, 0, 0);
      z = __builtin_amdgcn_mfma_f32_16x16x32_bf16(qf1, kb1, z, 0, 0, 0);
      sc[cb] = z;
    }

    float inv[4];
#pragma unroll
    for (int r = 0; r < 4; ++r) {
      float mx = -1e30f;
#pragma unroll
      for (int cb = 0; cb < 16; ++cb) mx = fmaxf(mx, sc[cb][r]);
      mx = fmaxf(mx, __shfl_xor(mx, 1));
      mx = fmaxf(mx, __shfl_xor(mx, 2));
      mx = fmaxf(mx, __shfl_xor(mx, 4));
      mx = fmaxf(mx, __shfl_xor(mx, 8));
      float sum = 0.f;
#pragma unroll
      for (int cb = 0; cb < 16; ++cb) {
        const float p = __expf((sc[cb][r] - mx) * 0.125f);
        sc[cb][r] = p;
        sum += p;
      }
      sum += __shfl_xor(sum, 1);
      sum += __shfl_xor(sum, 2);
      sum += __shfl_xor(sum, 4);
      sum += __shfl_xor(sum, 8);
      inv[r] = 1.f / sum;
    }

#pragma unroll
    for (int r = 0; r < 4; ++r)
#pragma unroll
      for (int cb = 0; cb < 16; ++cb)
        Pp[(cr * 4 + r) * 264 + cb * 16 + cc] = f2bf(sc[cb][r]);

    bf16x8 pf[8];
#pragma unroll
    for (int ks = 0; ks < 8; ++ks)
      pf[ks] = *(const bf16x8*)&Pp[cc * 264 + ks * 32 + cr * 8];
    f32x4 o[4] = {};
#pragma unroll
    for (int db = 0; db < 4; ++db)
#pragma unroll
      for (int ks = 0; ks < 8; ++ks) {
        const bf16x8 bv = *(const bf16x8*)&Vt[(db * 16 + cc) * 264 + ks * 32 + cr * 8];
        o[db] = __builtin_amdgcn_mfma_f32_16x16x32_bf16(pf[ks], bv, o[db], 0, 0, 0);
      }

#pragma unroll
    for (int db = 0; db < 4; ++db)
#pragma unroll
      for (int r = 0; r < 4; ++r) {
        const int qr = qrow0 + cr * 4 + r;
        x[base + (size_t)qr * 1024 + db * 16 + cc] = f2bf(o[db][r] * inv[r]);
      }
  }
}

// ---- launch ----------------------------------------------------------------

extern "C" void kernel_launch(void* const* d_in, const int* in_sizes, int n_in,
                              void* d_out, int out_size, void* d_ws, size_t ws_size,
                              hipStream_t stream) {
  const float* query = (const float*)d_in[0];
  const float* key_  = (const float*)d_in[1];
  const float* value = (const float*)d_in[2];
  const float* Wq = (const float*)d_in[3];
  const float* bq = (const float*)d_in[4];
  const float* Wk = (const float*)d_in[5];
  const float* bk = (const float*)d_in[6];
  const float* Wv = (const float*)d_in[7];
  const float* bv = (const float*)d_in[8];
  const float* Wo = (const float*)d_in[9];
  const float* bo = (const float*)d_in[10];
  float* out = (float*)d_out;

  const size_t MN = (size_t)16384 * 1024;
  const size_t WN = (size_t)1024 * 1024;
  ushort* qb = (ushort*)d_ws;
  ushort* kb = qb + MN;
  ushort* vb = kb + MN;
  ushort* wqb = vb + MN;
  ushort* wkb = wqb + WN;
  ushort* wvb = wkb + WN;
  ushort* wob = wvb + WN;
  ushort* qp = wob + WN;
  ushort* kp = qp + MN;
  ushort* vp = kp + MN;

  const dim3 blk(256);
  const dim3 ggrid(128 * 8);  // 1024 workgroups, 4+ resident blocks/CU

  cvt_qkv<<<dim3(3 * 1024), blk, 0, stream>>>(query, key_, value, qb, kb, vb);
  cvt_w<<<dim3(4 * 128), blk, 0, stream>>>(Wq, Wk, Wv, Wo, wqb, wkb, wvb, wob);

  gemm_2ph<1><<<ggrid, blk, 0, stream>>>(qb, wqb, bq, qp, 1024, 1024);
  gemm_2ph<1><<<ggrid, blk, 0, stream>>>(kb, wkb, bk, kp, 1024, 1024);
  gemm_2ph<1><<<ggrid, blk, 0, stream>>>(vb, wvb, bv, vp, 1024, 1024);

  attn_kernel<<<dim3(1024), blk, 0, stream>>>(qp, kp, vp, qp /*in-place*/);

  gemm_2ph<0><<<ggrid, blk, 0, stream>>>(qp, wob, bo, out, 1024, 1024);
}

// Round 14
// 313.536 us; speedup vs baseline: 1.1386x; 1.0256x over previous
//
#include <hip/hip_runtime.h>
#include <hip/hip_bf16.h>

typedef __attribute__((ext_vector_type(8))) __bf16 bf16x8;
typedef __attribute__((ext_vector_type(4))) float f32x4;

#define DEVI static __device__ __forceinline__

// ---- helpers ---------------------------------------------------------------

DEVI ushort f2bf(float f) {
  unsigned u = __builtin_bit_cast(unsigned, f);
  return (ushort)((u + 0x7fffu + ((u >> 16) & 1u)) >> 16);
}

union BF8 { unsigned u[4]; bf16x8 v; };

DEVI bf16x8 cvt8(const float* __restrict__ p) {
  const f32x4 a = *(const f32x4*)p;
  const f32x4 b = *(const f32x4*)(p + 4);
  BF8 r;
  asm("v_cvt_pk_bf16_f32 %0, %1, %2" : "=v"(r.u[0]) : "v"(a.x), "v"(a.y));
  asm("v_cvt_pk_bf16_f32 %0, %1, %2" : "=v"(r.u[1]) : "v"(a.z), "v"(a.w));
  asm("v_cvt_pk_bf16_f32 %0, %1, %2" : "=v"(r.u[2]) : "v"(b.x), "v"(b.y));
  asm("v_cvt_pk_bf16_f32 %0, %1, %2" : "=v"(r.u[3]) : "v"(b.z), "v"(b.w));
  return r.v;
}

DEVI bf16x8 cvt8r(f32x4 a, f32x4 b) {
  BF8 r;
  asm("v_cvt_pk_bf16_f32 %0, %1, %2" : "=v"(r.u[0]) : "v"(a.x), "v"(a.y));
  asm("v_cvt_pk_bf16_f32 %0, %1, %2" : "=v"(r.u[1]) : "v"(a.z), "v"(a.w));
  asm("v_cvt_pk_bf16_f32 %0, %1, %2" : "=v"(r.u[2]) : "v"(b.x), "v"(b.y));
  asm("v_cvt_pk_bf16_f32 %0, %1, %2" : "=v"(r.u[3]) : "v"(b.z), "v"(b.w));
  return r.v;
}

DEVI void gload16(const void* g, void* l) {
  __builtin_amdgcn_global_load_lds(
      (const __attribute__((address_space(1))) unsigned*)g,
      (__attribute__((address_space(3))) unsigned*)l, 16, 0, 0);
}

DEVI int xcd_swizzle(int bid, int nwg) {
  return (bid & 7) * (nwg >> 3) + (bid >> 3);
}

// ---- converts --------------------------------------------------------------

__global__ __launch_bounds__(256) void cvt_qkv(
    const float* __restrict__ q, const float* __restrict__ k,
    const float* __restrict__ v, ushort* __restrict__ oq,
    ushort* __restrict__ ok2, ushort* __restrict__ ov) {
  const int s = blockIdx.x >> 10;          // 0..2 (uniform per block)
  const int tb = blockIdx.x & 1023;
  const float* src = s == 0 ? q : (s == 1 ? k : v);
  ushort* dst = s == 0 ? oq : (s == 1 ? ok2 : ov);
  const size_t base = (size_t)tb * 2048 + threadIdx.x;

  f32x4 va[8], vb[8];
#pragma unroll
  for (int j = 0; j < 8; ++j) {
    const float* p = src + (base + j * 256) * 8;
    va[j] = __builtin_nontemporal_load((const f32x4*)p);
    vb[j] = __builtin_nontemporal_load((const f32x4*)(p + 4));
  }
#pragma unroll
  for (int j = 0; j < 8; ++j)
    *(bf16x8*)(dst + (base + j * 256) * 8) = cvt8r(va[j], vb[j]);
}

__global__ __launch_bounds__(256) void cvt_w(
    const float* __restrict__ wq, const float* __restrict__ wk,
    const float* __restrict__ wv, const float* __restrict__ wo,
    ushort* __restrict__ oq, ushort* __restrict__ ok2,
    ushort* __restrict__ ov, ushort* __restrict__ oo) {
  const int s = blockIdx.x >> 7;           // 0..3
  const int tb = blockIdx.x & 127;
  const float* src = s == 0 ? wq : (s == 1 ? wk : (s == 2 ? wv : wo));
  ushort* dst = s == 0 ? oq : (s == 1 ? ok2 : (s == 2 ? ov : oo));
  const unsigned G = 128 * 256;
  const unsigned t = tb * 256 + threadIdx.x;
#pragma unroll
  for (int j = 0; j < 4; ++j) {
    const size_t i = (size_t)t + (size_t)j * G;
    *(bf16x8*)(dst + i * 8) = cvt8(src + i * 8);
  }
}

// ---- GEMM (bf16 x bf16): C[M,N] = A @ W^T + bias ---------------------------
// 128x128 tile, BK=32, 256 threads, 2-phase double-buffered LDS (measured
// best structure here: ~58 us). OUT: 0=f32, 1=bf16, 2=bf16 TRANSPOSED
// (C^T[col][row], row-stride 16384) for producing V^T for attention.

template <int OUT>
__global__ __launch_bounds__(256) void gemm_2ph(
    const ushort* __restrict__ A, const ushort* __restrict__ B,
    const float* __restrict__ bias, void* __restrict__ Cp, int N, int K) {
  __shared__ __align__(16) ushort As[2][128 * 32];
  __shared__ __align__(16) ushort Bs[2][128 * 32];
  const int tid = threadIdx.x, lane = tid & 63;
  const int wv = tid >> 6, wr = wv >> 1, wc = wv & 1;
  const int cc = lane & 15, cr = lane >> 4;
  const int ntiles = N >> 7;
  const int work = xcd_swizzle(blockIdx.x, gridDim.x);
  const size_t m0 = (size_t)(work / ntiles) * 128;
  const size_t n0 = (size_t)(work % ntiles) * 128;

  const int ch0 = tid, ch1 = tid + 256;
  const int row0 = ch0 >> 2, u0 = ch0 & 3;
  const int row1 = ch1 >> 2, u1 = ch1 & 3;
  const int sw0 = (u0 ^ ((row0 >> 1) & 3)) * 8;
  const int sw1 = (u1 ^ ((row1 >> 1) & 3)) * 8;
  const ushort* a0 = A + (m0 + row0) * (size_t)K + sw0;
  const ushort* a1 = A + (m0 + row1) * (size_t)K + sw1;
  const ushort* b0 = B + (n0 + row0) * (size_t)K + sw0;
  const ushort* b1 = B + (n0 + row1) * (size_t)K + sw1;

  auto stage = [&](int bf, int kt) {
    gload16(a0 + kt, &As[bf][ch0 * 8]);
    gload16(a1 + kt, &As[bf][ch1 * 8]);
    gload16(b0 + kt, &Bs[bf][ch0 * 8]);
    gload16(b1 + kt, &Bs[bf][ch1 * 8]);
  };

  f32x4 acc[4][4] = {};
  const int nt = K >> 5;

  stage(0, 0);
  for (int t = 0; t < nt; ++t) {
    const int cur = t & 1;
    if (t + 1 < nt) {
      stage(cur ^ 1, (t + 1) << 5);
      asm volatile("s_waitcnt vmcnt(4)" ::: "memory");
    } else {
      asm volatile("s_waitcnt vmcnt(0)" ::: "memory");
    }
    __builtin_amdgcn_s_barrier();
    asm volatile("" ::: "memory");

    bf16x8 af[4], bfr[4];
#pragma unroll
    for (int m = 0; m < 4; ++m) {
      const int row = wr * 64 + m * 16 + cc;
      af[m] = *(const bf16x8*)&As[cur][row * 32 + (cr ^ ((row >> 1) & 3)) * 8];
    }
#pragma unroll
    for (int n = 0; n < 4; ++n) {
      const int row = wc * 64 + n * 16 + cc;
      bfr[n] = *(const bf16x8*)&Bs[cur][row * 32 + (cr ^ ((row >> 1) & 3)) * 8];
    }
#pragma unroll
    for (int m = 0; m < 4; ++m)
#pragma unroll
      for (int n = 0; n < 4; ++n)
        acc[m][n] =
            __builtin_amdgcn_mfma_f32_16x16x32_bf16(af[m], bfr[n], acc[m][n], 0, 0, 0);

    asm volatile("" ::: "memory");
    __builtin_amdgcn_s_barrier();
  }

#pragma unroll
  for (int n = 0; n < 4; ++n) {
    const size_t col = n0 + wc * 64 + n * 16 + cc;
    const float bval = bias[col];
#pragma unroll
    for (int m = 0; m < 4; ++m) {
      const size_t row0_ = m0 + wr * 64 + m * 16 + cr * 4;
#pragma unroll
      for (int r = 0; r < 4; ++r) {
        const float val = acc[m][n][r] + bval;
        if constexpr (OUT == 0)
          ((float*)Cp)[(row0_ + r) * N + col] = val;
        else if constexpr (OUT == 1)
          ((ushort*)Cp)[(row0_ + r) * N + col] = f2bf(val);
        else  // transposed bf16: C^T[col][row], row-stride 16384
          ((ushort*)Cp)[col * 16384 + row0_ + r] = f2bf(val);
      }
    }
  }
}

// ---- windowed attention ----------------------------------------------------
// grid = 1024 (one per b,h,window), 512 threads = 8 waves x 32 q-rows.
// q/k: bf16 [B*S, 1024] col = h*64+dk. vt: bf16 V^T [1024][16384] (from the
// V-GEMM transposed epilogue). K and V^T staged in LDS with 8-slot XOR
// swizzle via pre-swizzled global source (both-sides rule). Output over q.

__global__ __launch_bounds__(512) void attn_kernel(
    const ushort* __restrict__ q, const ushort* __restrict__ k,
    const ushort* __restrict__ vt, ushort* __restrict__ x) {
  __shared__ __align__(16) ushort Ks[256 * 64];     // 32.8 KB, swizzled
  __shared__ __align__(16) ushort Vt[64 * 256];     // 32.8 KB, swizzled
  __shared__ ushort Pw[8][16 * 264];                // 67.6 KB
  const int bid = blockIdx.x;
  const int w = bid & 15, h = (bid >> 4) & 15, b = bid >> 8;
  const int tid = threadIdx.x, lane = tid & 63, wv = tid >> 6;
  const int cc = lane & 15, cr = lane >> 4;
  const size_t base = ((size_t)b * 4096 + (size_t)w * 256) * 1024 + h * 64;
  const size_t vbase = ((size_t)h * 64) * 16384 + (size_t)b * 4096 + w * 256;

  // stage K: 2048 16B units; unit u: row=u>>3, slot=u&7, gcol=(slot^(row&7))*8
#pragma unroll
  for (int i = 0; i < 4; ++i) {
    const int u = tid + i * 512;
    const int row = u >> 3, slot = u & 7;
    gload16(k + base + (size_t)row * 1024 + ((slot ^ (row & 7)) << 3),
            &Ks[u * 8]);
  }
  // stage V^T: 2048 units; row=dk=u>>5, slot=u&31, gs=(slot^(dk&7))*8
#pragma unroll
  for (int i = 0; i < 4; ++i) {
    const int u = tid + i * 512;
    const int dk = u >> 5, slot = u & 31;
    gload16(vt + vbase + (size_t)dk * 16384 + (((slot & 24) | ((slot ^ dk) & 7)) << 3),
            &Vt[u * 8]);
  }
  __syncthreads();

  ushort* Pp = Pw[wv];
  for (int c = 0; c < 2; ++c) {
    const int qrow0 = wv * 32 + c * 16;
    const ushort* qp = q + base + (size_t)(qrow0 + cc) * 1024 + cr * 8;
    const bf16x8 qf0 = *(const bf16x8*)qp;
    const bf16x8 qf1 = *(const bf16x8*)(qp + 32);

    f32x4 sc[16];
#pragma unroll
    for (int cb = 0; cb < 16; ++cb) {
      const int row = cb * 16 + cc;
      const bf16x8 kb0 = *(const bf16x8*)&Ks[row * 64 + ((cr ^ (row & 7)) << 3)];
      const bf16x8 kb1 =
          *(const bf16x8*)&Ks[row * 64 + (((4 + cr) ^ (row & 7)) << 3)];
      f32x4 z = {0.f, 0.f, 0.f, 0.f};
      z = __builtin_amdgcn_mfma_f32_16x16x32_bf16(qf0, kb0, z, 0, 0, 0);
      z = __builtin_amdgcn_mfma_f32_16x16x32_bf16(qf1, kb1, z, 0, 0, 0);
      sc[cb] = z;
    }

    float inv[4];
#pragma unroll
    for (int r = 0; r < 4; ++r) {
      float mx = -1e30f;
#pragma unroll
      for (int cb = 0; cb < 16; ++cb) mx = fmaxf(mx, sc[cb][r]);
      mx = fmaxf(mx, __shfl_xor(mx, 1));
      mx = fmaxf(mx, __shfl_xor(mx, 2));
      mx = fmaxf(mx, __shfl_xor(mx, 4));
      mx = fmaxf(mx, __shfl_xor(mx, 8));
      float sum = 0.f;
#pragma unroll
      for (int cb = 0; cb < 16; ++cb) {
        const float p = __expf((sc[cb][r] - mx) * 0.125f);
        sc[cb][r] = p;
        sum += p;
      }
      sum += __shfl_xor(sum, 1);
      sum += __shfl_xor(sum, 2);
      sum += __shfl_xor(sum, 4);
      sum += __shfl_xor(sum, 8);
      inv[r] = 1.f / sum;
    }

#pragma unroll
    for (int r = 0; r < 4; ++r)
#pragma unroll
      for (int cb = 0; cb < 16; ++cb)
        Pp[(cr * 4 + r) * 264 + cb * 16 + cc] = f2bf(sc[cb][r]);

    bf16x8 pf[8];
#pragma unroll
    for (int ks = 0; ks < 8; ++ks)
      pf[ks] = *(const bf16x8*)&Pp[cc * 264 + ks * 32 + cr * 8];
    f32x4 o[4] = {};
#pragma unroll
    for (int db = 0; db < 4; ++db) {
      const int row = db * 16 + cc;
#pragma unroll
      for (int ks = 0; ks < 8; ++ks) {
        const int gu = ks * 4 + cr;
        const int lu = (gu & 24) | ((gu ^ row) & 7);
        const bf16x8 bv = *(const bf16x8*)&Vt[row * 256 + lu * 8];
        o[db] = __builtin_amdgcn_mfma_f32_16x16x32_bf16(pf[ks], bv, o[db], 0, 0, 0);
      }
    }

#pragma unroll
    for (int db = 0; db < 4; ++db)
#pragma unroll
      for (int r = 0; r < 4; ++r) {
        const int qr = qrow0 + cr * 4 + r;
        x[base + (size_t)qr * 1024 + db * 16 + cc] = f2bf(o[db][r] * inv[r]);
      }
  }
}

// ---- launch ----------------------------------------------------------------

extern "C" void kernel_launch(void* const* d_in, const int* in_sizes, int n_in,
                              void* d_out, int out_size, void* d_ws, size_t ws_size,
                              hipStream_t stream) {
  const float* query = (const float*)d_in[0];
  const float* key_  = (const float*)d_in[1];
  const float* value = (const float*)d_in[2];
  const float* Wq = (const float*)d_in[3];
  const float* bq = (const float*)d_in[4];
  const float* Wk = (const float*)d_in[5];
  const float* bk = (const float*)d_in[6];
  const float* Wv = (const float*)d_in[7];
  const float* bv = (const float*)d_in[8];
  const float* Wo = (const float*)d_in[9];
  const float* bo = (const float*)d_in[10];
  float* out = (float*)d_out;

  const size_t MN = (size_t)16384 * 1024;
  const size_t WN = (size_t)1024 * 1024;
  ushort* qb = (ushort*)d_ws;
  ushort* kb = qb + MN;
  ushort* vb = kb + MN;
  ushort* wqb = vb + MN;
  ushort* wkb = wqb + WN;
  ushort* wvb = wkb + WN;
  ushort* wob = wvb + WN;
  ushort* qp = wob + WN;
  ushort* kp = qp + MN;
  ushort* vtp = kp + MN;   // V^T [1024][16384]

  const dim3 b256(256), b512(512);
  const dim3 ggrid(128 * 8);  // 1024 workgroups

  cvt_qkv<<<dim3(3 * 1024), b256, 0, stream>>>(query, key_, value, qb, kb, vb);
  cvt_w<<<dim3(4 * 128), b256, 0, stream>>>(Wq, Wk, Wv, Wo, wqb, wkb, wvb, wob);

  gemm_2ph<1><<<ggrid, b256, 0, stream>>>(qb, wqb, bq, qp, 1024, 1024);
  gemm_2ph<1><<<ggrid, b256, 0, stream>>>(kb, wkb, bk, kp, 1024, 1024);
  gemm_2ph<2><<<ggrid, b256, 0, stream>>>(vb, wvb, bv, vtp, 1024, 1024);

  attn_kernel<<<dim3(1024), b512, 0, stream>>>(qp, kp, vtp, qp /*in-place*/);

  gemm_2ph<0><<<ggrid, b256, 0, stream>>>(qp, wob, bo, out, 1024, 1024);
}

// Round 17
// 291.492 us; speedup vs baseline: 1.2247x; 1.0756x over previous
//
#include <hip/hip_runtime.h>
#include <hip/hip_bf16.h>

typedef __attribute__((ext_vector_type(8))) __bf16 bf16x8;
typedef __attribute__((ext_vector_type(4))) float f32x4;

#define DEVI static __device__ __forceinline__

// ---- helpers ---------------------------------------------------------------

DEVI ushort f2bf(float f) {
  unsigned u = __builtin_bit_cast(unsigned, f);
  return (ushort)((u + 0x7fffu + ((u >> 16) & 1u)) >> 16);
}

union BF8 { unsigned u[4]; bf16x8 v; };

DEVI bf16x8 cvt8(const float* __restrict__ p) {
  const f32x4 a = *(const f32x4*)p;
  const f32x4 b = *(const f32x4*)(p + 4);
  BF8 r;
  asm("v_cvt_pk_bf16_f32 %0, %1, %2" : "=v"(r.u[0]) : "v"(a.x), "v"(a.y));
  asm("v_cvt_pk_bf16_f32 %0, %1, %2" : "=v"(r.u[1]) : "v"(a.z), "v"(a.w));
  asm("v_cvt_pk_bf16_f32 %0, %1, %2" : "=v"(r.u[2]) : "v"(b.x), "v"(b.y));
  asm("v_cvt_pk_bf16_f32 %0, %1, %2" : "=v"(r.u[3]) : "v"(b.z), "v"(b.w));
  return r.v;
}

DEVI bf16x8 cvt8r(f32x4 a, f32x4 b) {
  BF8 r;
  asm("v_cvt_pk_bf16_f32 %0, %1, %2" : "=v"(r.u[0]) : "v"(a.x), "v"(a.y));
  asm("v_cvt_pk_bf16_f32 %0, %1, %2" : "=v"(r.u[1]) : "v"(a.z), "v"(a.w));
  asm("v_cvt_pk_bf16_f32 %0, %1, %2" : "=v"(r.u[2]) : "v"(b.x), "v"(b.y));
  asm("v_cvt_pk_bf16_f32 %0, %1, %2" : "=v"(r.u[3]) : "v"(b.z), "v"(b.w));
  return r.v;
}

DEVI void gload16(const void* g, void* l) {
  __builtin_amdgcn_global_load_lds(
      (const __attribute__((address_space(1))) unsigned*)g,
      (__attribute__((address_space(3))) unsigned*)l, 16, 0, 0);
}

DEVI int xcd_swizzle(int bid, int nwg) {
  return (bid & 7) * (nwg >> 3) + (bid >> 3);
}

DEVI f32x4 mfma16(bf16x8 a, bf16x8 b, f32x4 c) {
  return __builtin_amdgcn_mfma_f32_16x16x32_bf16(a, b, c, 0, 0, 0);
}

// ---- converts --------------------------------------------------------------

__global__ __launch_bounds__(256) void cvt_qkv(
    const float* __restrict__ q, const float* __restrict__ k,
    const float* __restrict__ v, ushort* __restrict__ oq,
    ushort* __restrict__ ok2, ushort* __restrict__ ov) {
  const int s = blockIdx.x >> 10;
  const int tb = blockIdx.x & 1023;
  const float* src = s == 0 ? q : (s == 1 ? k : v);
  ushort* dst = s == 0 ? oq : (s == 1 ? ok2 : ov);
  const size_t base = (size_t)tb * 2048 + threadIdx.x;

  f32x4 va[8], vb[8];
#pragma unroll
  for (int j = 0; j < 8; ++j) {
    const float* p = src + (base + j * 256) * 8;
    va[j] = __builtin_nontemporal_load((const f32x4*)p);
    vb[j] = __builtin_nontemporal_load((const f32x4*)(p + 4));
  }
#pragma unroll
  for (int j = 0; j < 8; ++j)
    *(bf16x8*)(dst + (base + j * 256) * 8) = cvt8r(va[j], vb[j]);
}

__global__ __launch_bounds__(256) void cvt_w(
    const float* __restrict__ wq, const float* __restrict__ wk,
    const float* __restrict__ wv, const float* __restrict__ wo,
    ushort* __restrict__ oq, ushort* __restrict__ ok2,
    ushort* __restrict__ ov, ushort* __restrict__ oo) {
  const int s = blockIdx.x >> 7;
  const int tb = blockIdx.x & 127;
  const float* src = s == 0 ? wq : (s == 1 ? wk : (s == 2 ? wv : wo));
  ushort* dst = s == 0 ? oq : (s == 1 ? ok2 : (s == 2 ? ov : oo));
  const unsigned G = 128 * 256;
  const unsigned t = tb * 256 + threadIdx.x;
#pragma unroll
  for (int j = 0; j < 4; ++j) {
    const size_t i = (size_t)t + (size_t)j * G;
    *(bf16x8*)(dst + i * 8) = cvt8(src + i * 8);
  }
}

// ---- GEMM: 256x256 tile, BK=32, 512 threads, fine-phase pipeline -----------
// 8 waves (2M x 4N), per-wave 128x64 output (8x4 f32x4 acc). 4 rotating LDS
// buffers (A[256][32]+B[256][32] each, 128 KB total); tile k stages tile k+3
// (lead 3 = 4-6 phases >= HBM latency), 2 gload_lds per phase. Two fine
// phases per K-tile: {ds_read frags || stage -> barrier -> lgkmcnt(0) ->
// setprio(1) 16 MFMA setprio(0) -> barrier}. vmcnt(8) ONCE per tile at the
// LAST phase, before its ending barrier, guarding tile k+1's loads (ledger:
// outstanding <= tiles k+1,k+2,k+3 = 12 loads; allow 8 -> k+1 landed; the
// ending barrier publishes all waves' stages for the next phase-0 ds_reads).
// LDS reads use the 4-slot XOR swizzle measured conflict-free in r7/r8.

template <int OUT>
__global__ __launch_bounds__(512, 2) void gemm_8ph(
    const ushort* __restrict__ A, const ushort* __restrict__ B,
    const float* __restrict__ bias, void* __restrict__ Cp, int N, int K) {
  __shared__ __align__(16) ushort Asm[4][8192];  // 4 x 16 KB
  __shared__ __align__(16) ushort Bsm[4][8192];
  const int tid = threadIdx.x, lane = tid & 63;
  const int wv = tid >> 6;
  const int wr = wv >> 2, wc = wv & 3;   // 2 M-waves x 4 N-waves
  const int cc = lane & 15, cr = lane >> 4;
  const int nw = N >> 8;
  const int work = xcd_swizzle(blockIdx.x, gridDim.x);
  const size_t m0 = (size_t)(work / nw) * 256;
  const size_t n0 = (size_t)(work % nw) * 256;

  // staging: unit u = row*4 + slot (16B units); global col = (slot^((row>>1)&3))*8
  const ushort *ag[2], *bg[2];
#pragma unroll
  for (int h = 0; h < 2; ++h) {
    const int u = tid + h * 512;
    const int row = u >> 2, slot = u & 3;
    const int gc = (slot ^ ((row >> 1) & 3)) * 8;
    ag[h] = A + (m0 + row) * (size_t)K + gc;
    bg[h] = B + (n0 + row) * (size_t)K + gc;
  }

  auto stageh = [&](int buf, int kt, int h) {
    gload16(ag[h] + kt, &Asm[buf][(tid + h * 512) * 8]);
    gload16(bg[h] + kt, &Bsm[buf][(tid + h * 512) * 8]);
  };

  f32x4 acc[8][4] = {};
  const int nt = K >> 5;  // 32

  // fragment LDS element offsets
  int aoff[8], boff[4];
#pragma unroll
  for (int m = 0; m < 8; ++m) {
    const int row = wr * 128 + m * 16 + cc;
    aoff[m] = (row * 4 + (cr ^ ((row >> 1) & 3))) * 8;
  }
#pragma unroll
  for (int n = 0; n < 4; ++n) {
    const int row = wc * 64 + n * 16 + cc;
    boff[n] = (row * 4 + (cr ^ ((row >> 1) & 3))) * 8;
  }

  // prologue: stage tiles 0,1,2; drain tile 0; publish
#pragma unroll
  for (int p = 0; p < 3; ++p) {
    stageh(p, p << 5, 0);
    stageh(p, p << 5, 1);
  }
  asm volatile("s_waitcnt vmcnt(8)" ::: "memory");
  __builtin_amdgcn_s_barrier();
  asm volatile("" ::: "memory");

  for (int k = 0; k < nt; ++k) {
    const ushort* Ab = Asm[k & 3];
    const ushort* Bb = Bsm[k & 3];
    const int wb = (k + 3) & 3;
    const bool more = (k + 3 < nt);
    bf16x8 bf[4], af[4];

    // ---- phase 0: B-frags + A m0-3, stage h0, 16 MFMA ----
#pragma unroll
    for (int n = 0; n < 4; ++n) bf[n] = *(const bf16x8*)&Bb[boff[n]];
#pragma unroll
    for (int m = 0; m < 4; ++m) af[m] = *(const bf16x8*)&Ab[aoff[m]];
    if (more) stageh(wb, (k + 3) << 5, 0);
    __builtin_amdgcn_s_barrier();
    asm volatile("s_waitcnt lgkmcnt(0)" ::: "memory");
    __builtin_amdgcn_s_setprio(1);
#pragma unroll
    for (int m = 0; m < 4; ++m)
#pragma unroll
      for (int n = 0; n < 4; ++n)
        acc[m][n] = mfma16(af[m], bf[n], acc[m][n]);
    __builtin_amdgcn_s_setprio(0);
    asm volatile("" ::: "memory");
    __builtin_amdgcn_s_barrier();

    // ---- phase 1: A m4-7, stage h1, per-tile vmcnt guard, 16 MFMA ----
#pragma unroll
    for (int m = 0; m < 4; ++m) af[m] = *(const bf16x8*)&Ab[aoff[4 + m]];
    if (more) stageh(wb, (k + 3) << 5, 1);
    if (k < nt - 3) {
      asm volatile("s_waitcnt vmcnt(8)" ::: "memory");
    } else if (k == nt - 3) {
      asm volatile("s_waitcnt vmcnt(4)" ::: "memory");
    } else if (k == nt - 2) {
      asm volatile("s_waitcnt vmcnt(0)" ::: "memory");
    }
    __builtin_amdgcn_s_barrier();
    asm volatile("s_waitcnt lgkmcnt(0)" ::: "memory");
    __builtin_amdgcn_s_setprio(1);
#pragma unroll
    for (int m = 0; m < 4; ++m)
#pragma unroll
      for (int n = 0; n < 4; ++n)
        acc[4 + m][n] = mfma16(af[m], bf[n], acc[4 + m][n]);
    __builtin_amdgcn_s_setprio(0);
    asm volatile("" ::: "memory");
    __builtin_amdgcn_s_barrier();
  }

  // epilogue
#pragma unroll
  for (int n = 0; n < 4; ++n) {
    const size_t col = n0 + wc * 64 + n * 16 + cc;
    const float bval = bias[col];
#pragma unroll
    for (int m = 0; m < 8; ++m) {
      const size_t row0 = m0 + wr * 128 + m * 16 + cr * 4;
#pragma unroll
      for (int r = 0; r < 4; ++r) {
        const float val = acc[m][n][r] + bval;
        if constexpr (OUT == 0)
          ((float*)Cp)[(row0 + r) * N + col] = val;
        else if constexpr (OUT == 1)
          ((ushort*)Cp)[(row0 + r) * N + col] = f2bf(val);
        else  // transposed bf16: C^T[col][row], row-stride 16384
          ((ushort*)Cp)[col * 16384 + row0 + r] = f2bf(val);
      }
    }
  }
}

// ---- windowed attention ----------------------------------------------------
// grid = 1024 (one per b,h,window), 512 threads = 8 waves x 32 q-rows.
// K and V^T staged with 8-slot XOR swizzle (both-sides rule). Output over q.

__global__ __launch_bounds__(512) void attn_kernel(
    const ushort* __restrict__ q, const ushort* __restrict__ k,
    const ushort* __restrict__ vt, ushort* __restrict__ x) {
  __shared__ __align__(16) ushort Ks[256 * 64];
  __shared__ __align__(16) ushort Vt[64 * 256];
  __shared__ ushort Pw[8][16 * 264];
  const int bid = blockIdx.x;
  const int w = bid & 15, h = (bid >> 4) & 15, b = bid >> 8;
  const int tid = threadIdx.x, lane = tid & 63, wv = tid >> 6;
  const int cc = lane & 15, cr = lane >> 4;
  const size_t base = ((size_t)b * 4096 + (size_t)w * 256) * 1024 + h * 64;
  const size_t vbase = ((size_t)h * 64) * 16384 + (size_t)b * 4096 + w * 256;

#pragma unroll
  for (int i = 0; i < 4; ++i) {
    const int u = tid + i * 512;
    const int row = u >> 3, slot = u & 7;
    gload16(k + base + (size_t)row * 1024 + ((slot ^ (row & 7)) << 3),
            &Ks[u * 8]);
  }
#pragma unroll
  for (int i = 0; i < 4; ++i) {
    const int u = tid + i * 512;
    const int dk = u >> 5, slot = u & 31;
    gload16(vt + vbase + (size_t)dk * 16384 + (((slot & 24) | ((slot ^ dk) & 7)) << 3),
            &Vt[u * 8]);
  }
  __syncthreads();

  ushort* Pp = Pw[wv];
  for (int c = 0; c < 2; ++c) {
    const int qrow0 = wv * 32 + c * 16;
    const ushort* qp = q + base + (size_t)(qrow0 + cc) * 1024 + cr * 8;
    const bf16x8 qf0 = *(const bf16x8*)qp;
    const bf16x8 qf1 = *(const bf16x8*)(qp + 32);

    f32x4 sc[16];
#pragma unroll
    for (int cb = 0; cb < 16; ++cb) {
      const int row = cb * 16 + cc;
      const bf16x8 kb0 = *(const bf16x8*)&Ks[row * 64 + ((cr ^ (row & 7)) << 3)];
      const bf16x8 kb1 =
          *(const bf16x8*)&Ks[row * 64 + (((4 + cr) ^ (row & 7)) << 3)];
      f32x4 z = {0.f, 0.f, 0.f, 0.f};
      z = mfma16(qf0, kb0, z);
      z = mfma16(qf1, kb1, z);
      sc[cb] = z;
    }

    float inv[4];
#pragma unroll
    for (int r = 0; r < 4; ++r) {
      float mx = -1e30f;
#pragma unroll
      for (int cb = 0; cb < 16; ++cb) mx = fmaxf(mx, sc[cb][r]);
      mx = fmaxf(mx, __shfl_xor(mx, 1));
      mx = fmaxf(mx, __shfl_xor(mx, 2));
      mx = fmaxf(mx, __shfl_xor(mx, 4));
      mx = fmaxf(mx, __shfl_xor(mx, 8));
      float sum = 0.f;
#pragma unroll
      for (int cb = 0; cb < 16; ++cb) {
        const float p = __expf((sc[cb][r] - mx) * 0.125f);
        sc[cb][r] = p;
        sum += p;
      }
      sum += __shfl_xor(sum, 1);
      sum += __shfl_xor(sum, 2);
      sum += __shfl_xor(sum, 4);
      sum += __shfl_xor(sum, 8);
      inv[r] = 1.f / sum;
    }

#pragma unroll
    for (int r = 0; r < 4; ++r)
#pragma unroll
      for (int cb = 0; cb < 16; ++cb)
        Pp[(cr * 4 + r) * 264 + cb * 16 + cc] = f2bf(sc[cb][r]);

    bf16x8 pf[8];
#pragma unroll
    for (int ks = 0; ks < 8; ++ks)
      pf[ks] = *(const bf16x8*)&Pp[cc * 264 + ks * 32 + cr * 8];
    f32x4 o[4] = {};
#pragma unroll
    for (int db = 0; db < 4; ++db) {
      const int row = db * 16 + cc;
#pragma unroll
      for (int ks = 0; ks < 8; ++ks) {
        const int gu = ks * 4 + cr;
        const int lu = (gu & 24) | ((gu ^ row) & 7);
        const bf16x8 bv = *(const bf16x8*)&Vt[row * 256 + lu * 8];
        o[db] = mfma16(pf[ks], bv, o[db]);
      }
    }

#pragma unroll
    for (int db = 0; db < 4; ++db)
#pragma unroll
      for (int r = 0; r < 4; ++r) {
        const int qr = qrow0 + cr * 4 + r;
        x[base + (size_t)qr * 1024 + db * 16 + cc] = f2bf(o[db][r] * inv[r]);
      }
  }
}

// ---- launch ----------------------------------------------------------------

extern "C" void kernel_launch(void* const* d_in, const int* in_sizes, int n_in,
                              void* d_out, int out_size, void* d_ws, size_t ws_size,
                              hipStream_t stream) {
  const float* query = (const float*)d_in[0];
  const float* key_  = (const float*)d_in[1];
  const float* value = (const float*)d_in[2];
  const float* Wq = (const float*)d_in[3];
  const float* bq = (const float*)d_in[4];
  const float* Wk = (const float*)d_in[5];
  const float* bk = (const float*)d_in[6];
  const float* Wv = (const float*)d_in[7];
  const float* bv = (const float*)d_in[8];
  const float* Wo = (const float*)d_in[9];
  const float* bo = (const float*)d_in[10];
  float* out = (float*)d_out;

  const size_t MN = (size_t)16384 * 1024;
  const size_t WN = (size_t)1024 * 1024;
  ushort* qb = (ushort*)d_ws;
  ushort* kb = qb + MN;
  ushort* vb = kb + MN;
  ushort* wqb = vb + MN;
  ushort* wkb = wqb + WN;
  ushort* wvb = wkb + WN;
  ushort* wob = wvb + WN;
  ushort* qp = wob + WN;
  ushort* kp = qp + MN;
  ushort* vtp = kp + MN;   // V^T [1024][16384]

  const dim3 b256(256), b512(512);
  const dim3 ggrid(64 * 4);  // (16384/256)*(1024/256) = 256 blocks

  cvt_qkv<<<dim3(3 * 1024), b256, 0, stream>>>(query, key_, value, qb, kb, vb);
  cvt_w<<<dim3(4 * 128), b256, 0, stream>>>(Wq, Wk, Wv, Wo, wqb, wkb, wvb, wob);

  gemm_8ph<1><<<ggrid, b512, 0, stream>>>(qb, wqb, bq, qp, 1024, 1024);
  gemm_8ph<1><<<ggrid, b512, 0, stream>>>(kb, wkb, bk, kp, 1024, 1024);
  gemm_8ph<2><<<ggrid, b512, 0, stream>>>(vb, wvb, bv, vtp, 1024, 1024);

  attn_kernel<<<dim3(1024), b512, 0, stream>>>(qp, kp, vtp, qp /*in-place*/);

  gemm_8ph<0><<<ggrid, b512, 0, stream>>>(qp, wob, bo, out, 1024, 1024);
}

// Round 18
// 277.572 us; speedup vs baseline: 1.2861x; 1.0501x over previous
//
#include <hip/hip_runtime.h>
#include <hip/hip_bf16.h>

typedef __attribute__((ext_vector_type(8))) __bf16 bf16x8;
typedef __attribute__((ext_vector_type(4))) float f32x4;

#define DEVI static __device__ __forceinline__

// ---- helpers ---------------------------------------------------------------

DEVI ushort f2bf(float f) {
  unsigned u = __builtin_bit_cast(unsigned, f);
  return (ushort)((u + 0x7fffu + ((u >> 16) & 1u)) >> 16);
}

union BF8 { unsigned u[4]; bf16x8 v; };

DEVI bf16x8 cvt8(const float* __restrict__ p) {
  const f32x4 a = *(const f32x4*)p;
  const f32x4 b = *(const f32x4*)(p + 4);
  BF8 r;
  asm("v_cvt_pk_bf16_f32 %0, %1, %2" : "=v"(r.u[0]) : "v"(a.x), "v"(a.y));
  asm("v_cvt_pk_bf16_f32 %0, %1, %2" : "=v"(r.u[1]) : "v"(a.z), "v"(a.w));
  asm("v_cvt_pk_bf16_f32 %0, %1, %2" : "=v"(r.u[2]) : "v"(b.x), "v"(b.y));
  asm("v_cvt_pk_bf16_f32 %0, %1, %2" : "=v"(r.u[3]) : "v"(b.z), "v"(b.w));
  return r.v;
}

DEVI bf16x8 cvt8r(f32x4 a, f32x4 b) {
  BF8 r;
  asm("v_cvt_pk_bf16_f32 %0, %1, %2" : "=v"(r.u[0]) : "v"(a.x), "v"(a.y));
  asm("v_cvt_pk_bf16_f32 %0, %1, %2" : "=v"(r.u[1]) : "v"(a.z), "v"(a.w));
  asm("v_cvt_pk_bf16_f32 %0, %1, %2" : "=v"(r.u[2]) : "v"(b.x), "v"(b.y));
  asm("v_cvt_pk_bf16_f32 %0, %1, %2" : "=v"(r.u[3]) : "v"(b.z), "v"(b.w));
  return r.v;
}

DEVI void gload16(const void* g, void* l) {
  __builtin_amdgcn_global_load_lds(
      (const __attribute__((address_space(1))) unsigned*)g,
      (__attribute__((address_space(3))) unsigned*)l, 16, 0, 0);
}

DEVI int xcd_swizzle(int bid, int nwg) {
  return (bid & 7) * (nwg >> 3) + (bid >> 3);
}

DEVI f32x4 mfma16(bf16x8 a, bf16x8 b, f32x4 c) {
  return __builtin_amdgcn_mfma_f32_16x16x32_bf16(a, b, c, 0, 0, 0);
}

// ---- weight convert --------------------------------------------------------

__global__ __launch_bounds__(256) void cvt_w(
    const float* __restrict__ wq, const float* __restrict__ wk,
    const float* __restrict__ wv, const float* __restrict__ wo,
    ushort* __restrict__ oq, ushort* __restrict__ ok2,
    ushort* __restrict__ ov, ushort* __restrict__ oo) {
  const int s = blockIdx.x >> 7;
  const int tb = blockIdx.x & 127;
  const float* src = s == 0 ? wq : (s == 1 ? wk : (s == 2 ? wv : wo));
  ushort* dst = s == 0 ? oq : (s == 1 ? ok2 : (s == 2 ? ov : oo));
  const unsigned G = 128 * 256;
  const unsigned t = tb * 256 + threadIdx.x;
#pragma unroll
  for (int j = 0; j < 4; ++j) {
    const size_t i = (size_t)t + (size_t)j * G;
    *(bf16x8*)(dst + i * 8) = cvt8(src + i * 8);
  }
}

// ---- GEMM (bf16 A): 256x256 tile, BK=32, 512 threads, fine-phase -----------
// (verified round 17: ~42 us/dispatch at this shape)

template <int OUT>
__global__ __launch_bounds__(512, 2) void gemm_8ph(
    const ushort* __restrict__ A, const ushort* __restrict__ B,
    const float* __restrict__ bias, void* __restrict__ Cp, int N, int K) {
  __shared__ __align__(16) ushort Asm[4][8192];
  __shared__ __align__(16) ushort Bsm[4][8192];
  const int tid = threadIdx.x, lane = tid & 63;
  const int wv = tid >> 6;
  const int wr = wv >> 2, wc = wv & 3;
  const int cc = lane & 15, cr = lane >> 4;
  const int nw = N >> 8;
  const int work = xcd_swizzle(blockIdx.x, gridDim.x);
  const size_t m0 = (size_t)(work / nw) * 256;
  const size_t n0 = (size_t)(work % nw) * 256;

  const ushort *ag[2], *bg[2];
#pragma unroll
  for (int h = 0; h < 2; ++h) {
    const int u = tid + h * 512;
    const int row = u >> 2, slot = u & 3;
    const int gc = (slot ^ ((row >> 1) & 3)) * 8;
    ag[h] = A + (m0 + row) * (size_t)K + gc;
    bg[h] = B + (n0 + row) * (size_t)K + gc;
  }

  auto stageh = [&](int buf, int kt, int h) {
    gload16(ag[h] + kt, &Asm[buf][(tid + h * 512) * 8]);
    gload16(bg[h] + kt, &Bsm[buf][(tid + h * 512) * 8]);
  };

  f32x4 acc[8][4] = {};
  const int nt = K >> 5;

  int aoff[8], boff[4];
#pragma unroll
  for (int m = 0; m < 8; ++m) {
    const int row = wr * 128 + m * 16 + cc;
    aoff[m] = (row * 4 + (cr ^ ((row >> 1) & 3))) * 8;
  }
#pragma unroll
  for (int n = 0; n < 4; ++n) {
    const int row = wc * 64 + n * 16 + cc;
    boff[n] = (row * 4 + (cr ^ ((row >> 1) & 3))) * 8;
  }

#pragma unroll
  for (int p = 0; p < 3; ++p) {
    stageh(p, p << 5, 0);
    stageh(p, p << 5, 1);
  }
  asm volatile("s_waitcnt vmcnt(8)" ::: "memory");
  __builtin_amdgcn_s_barrier();
  asm volatile("" ::: "memory");

  for (int k = 0; k < nt; ++k) {
    const ushort* Ab = Asm[k & 3];
    const ushort* Bb = Bsm[k & 3];
    const int wb = (k + 3) & 3;
    const bool more = (k + 3 < nt);
    bf16x8 bf[4], af[4];

#pragma unroll
    for (int n = 0; n < 4; ++n) bf[n] = *(const bf16x8*)&Bb[boff[n]];
#pragma unroll
    for (int m = 0; m < 4; ++m) af[m] = *(const bf16x8*)&Ab[aoff[m]];
    if (more) stageh(wb, (k + 3) << 5, 0);
    __builtin_amdgcn_s_barrier();
    asm volatile("s_waitcnt lgkmcnt(0)" ::: "memory");
    __builtin_amdgcn_s_setprio(1);
#pragma unroll
    for (int m = 0; m < 4; ++m)
#pragma unroll
      for (int n = 0; n < 4; ++n)
        acc[m][n] = mfma16(af[m], bf[n], acc[m][n]);
    __builtin_amdgcn_s_setprio(0);
    asm volatile("" ::: "memory");
    __builtin_amdgcn_s_barrier();

#pragma unroll
    for (int m = 0; m < 4; ++m) af[m] = *(const bf16x8*)&Ab[aoff[4 + m]];
    if (more) stageh(wb, (k + 3) << 5, 1);
    if (k < nt - 3) {
      asm volatile("s_waitcnt vmcnt(8)" ::: "memory");
    } else if (k == nt - 3) {
      asm volatile("s_waitcnt vmcnt(4)" ::: "memory");
    } else if (k == nt - 2) {
      asm volatile("s_waitcnt vmcnt(0)" ::: "memory");
    }
    __builtin_amdgcn_s_barrier();
    asm volatile("s_waitcnt lgkmcnt(0)" ::: "memory");
    __builtin_amdgcn_s_setprio(1);
#pragma unroll
    for (int m = 0; m < 4; ++m)
#pragma unroll
      for (int n = 0; n < 4; ++n)
        acc[4 + m][n] = mfma16(af[m], bf[n], acc[4 + m][n]);
    __builtin_amdgcn_s_setprio(0);
    asm volatile("" ::: "memory");
    __builtin_amdgcn_s_barrier();
  }

#pragma unroll
  for (int n = 0; n < 4; ++n) {
    const size_t col = n0 + wc * 64 + n * 16 + cc;
    const float bval = bias[col];
#pragma unroll
    for (int m = 0; m < 8; ++m) {
      const size_t row0 = m0 + wr * 128 + m * 16 + cr * 4;
#pragma unroll
      for (int r = 0; r < 4; ++r) {
        const float val = acc[m][n][r] + bval;
        if constexpr (OUT == 0)
          ((float*)Cp)[(row0 + r) * N + col] = val;
        else if constexpr (OUT == 1)
          ((ushort*)Cp)[(row0 + r) * N + col] = f2bf(val);
        else
          ((ushort*)Cp)[col * 16384 + row0 + r] = f2bf(val);
      }
    }
  }
}

// ---- GEMM (f32 A, fused convert): same fine-phase structure ----------------
// A: global f32 -> regs (tile k-1 ph0 loads A(k+2)) -> cvt_pk -> swizzled
// ds_write_b128 at tile k ph1 (after MFMA; published by lgkmcnt(0)+barrier);
// consumed tile k+2 ph0. Two named reg sets, loop unrolled x2 (rule #20).
// B: gload_lds lead-3 as in gemm_8ph. vm-ops/tile = [4 A-reg, B#0 | B#1] = 6;
// guard at ph0(k) for B(k): vmcnt(17), tail 12/6/0.

template <int OUT>
__global__ __launch_bounds__(512, 2) void gemm_8ph_f32a(
    const float* __restrict__ A, const ushort* __restrict__ B,
    const float* __restrict__ bias, void* __restrict__ Cp, int N, int K) {
  __shared__ __align__(16) ushort Asm[4][8192];
  __shared__ __align__(16) ushort Bsm[4][8192];
  const int tid = threadIdx.x, lane = tid & 63;
  const int wv = tid >> 6;
  const int wr = wv >> 2, wc = wv & 3;
  const int cc = lane & 15, cr = lane >> 4;
  const int nw = N >> 8;
  const int work = xcd_swizzle(blockIdx.x, gridDim.x);
  const size_t m0 = (size_t)(work / nw) * 256;
  const size_t n0 = (size_t)(work % nw) * 256;

  // A reg-staging map: units u0=tid, u1=tid+512; 8 f32 each (2 f32x4)
  const float *af0, *af1;
  ushort *al0, *al1;
  {
    const int u0 = tid, r0 = u0 >> 2, s0 = u0 & 3;
    const int u1 = tid + 512, r1 = u1 >> 2, s1 = u1 & 3;
    af0 = A + (m0 + r0) * (size_t)K + (s0 ^ ((r0 >> 1) & 3)) * 8;
    af1 = A + (m0 + r1) * (size_t)K + (s1 ^ ((r1 >> 1) & 3)) * 8;
    al0 = &Asm[0][0] + u0 * 8;
    al1 = &Asm[0][0] + u1 * 8;
  }
  // B gload map
  const ushort* bg[2];
#pragma unroll
  for (int h = 0; h < 2; ++h) {
    const int u = tid + h * 512;
    const int row = u >> 2, slot = u & 3;
    bg[h] = B + (n0 + row) * (size_t)K + (slot ^ ((row >> 1) & 3)) * 8;
  }

  f32x4 acc[8][4] = {};
  const int nt = K >> 5;  // 32 (even; K >= 128 assumed)

  int aoff[8], boff[4];
#pragma unroll
  for (int m = 0; m < 8; ++m) {
    const int row = wr * 128 + m * 16 + cc;
    aoff[m] = (row * 4 + (cr ^ ((row >> 1) & 3))) * 8;
  }
#pragma unroll
  for (int n = 0; n < 4; ++n) {
    const int row = wc * 64 + n * 16 + cc;
    boff[n] = (row * 4 + (cr ^ ((row >> 1) & 3))) * 8;
  }

  // prologue: A(0),A(1) -> LDS via temp regs; SA = A(2); B(0),B(1),B(2)
  f32x4 sa0, sa1, sa2, sa3, sb0, sb1, sb2, sb3;
#pragma unroll
  for (int p = 0; p < 2; ++p) {
    const int kt = p << 5;
    sa0 = *(const f32x4*)(af0 + kt);  sa1 = *(const f32x4*)(af0 + kt + 4);
    sa2 = *(const f32x4*)(af1 + kt);  sa3 = *(const f32x4*)(af1 + kt + 4);
    *(bf16x8*)(al0 + p * 8192) = cvt8r(sa0, sa1);
    *(bf16x8*)(al1 + p * 8192) = cvt8r(sa2, sa3);
  }
  sa0 = *(const f32x4*)(af0 + 64);  sa1 = *(const f32x4*)(af0 + 68);
  sa2 = *(const f32x4*)(af1 + 64);  sa3 = *(const f32x4*)(af1 + 68);
#pragma unroll
  for (int p = 0; p < 3; ++p) {
    gload16(bg[0] + (p << 5), &Bsm[p][tid * 8]);
    gload16(bg[1] + (p << 5), &Bsm[p][(tid + 512) * 8]);
  }
  asm volatile("s_waitcnt vmcnt(0) lgkmcnt(0)" ::: "memory");
  __builtin_amdgcn_s_barrier();
  asm volatile("" ::: "memory");

  // one K-tile: SETW = reg set written at ph1 (holds A(k+2)); SETL loaded at
  // ph0 (receives A(k+3)). Guard values precomputed per k.
#define F32A_TILE(k, W0, W1, W2, W3, L0, L1, L2, L3)                          \
  {                                                                           \
    const ushort* Ab = Asm[(k) & 3];                                          \
    const ushort* Bb = Bsm[(k) & 3];                                          \
    const int wb = ((k) + 3) & 3;                                             \
    const bool more = ((k) + 3 < nt);                                         \
    bf16x8 bf[4], af[4];                                                      \
    _Pragma("unroll")                                                         \
    for (int n = 0; n < 4; ++n) bf[n] = *(const bf16x8*)&Bb[boff[n]];         \
    _Pragma("unroll")                                                         \
    for (int m = 0; m < 4; ++m) af[m] = *(const bf16x8*)&Ab[aoff[m]];         \
    if (more) {                                                               \
      const int kt = ((k) + 3) << 5;                                          \
      L0 = *(const f32x4*)(af0 + kt);  L1 = *(const f32x4*)(af0 + kt + 4);    \
      L2 = *(const f32x4*)(af1 + kt);  L3 = *(const f32x4*)(af1 + kt + 4);    \
      gload16(bg[0] + kt, &Bsm[wb][tid * 8]);                                 \
    }                                                                         \
    if ((k) < nt - 3) {                                                       \
      asm volatile("s_waitcnt vmcnt(17)" ::: "memory");                       \
    } else if ((k) == nt - 3) {                                               \
      asm volatile("s_waitcnt vmcnt(12)" ::: "memory");                       \
    } else if ((k) == nt - 2) {                                               \
      asm volatile("s_waitcnt vmcnt(6)" ::: "memory");                        \
    } else {                                                                  \
      asm volatile("s_waitcnt vmcnt(0)" ::: "memory");                        \
    }                                                                         \
    __builtin_amdgcn_s_barrier();                                             \
    asm volatile("s_waitcnt lgkmcnt(0)" ::: "memory");                        \
    __builtin_amdgcn_s_setprio(1);                                            \
    _Pragma("unroll")                                                         \
    for (int m = 0; m < 4; ++m)                                               \
      _Pragma("unroll")                                                       \
      for (int n = 0; n < 4; ++n) acc[m][n] = mfma16(af[m], bf[n], acc[m][n]);\
    __builtin_amdgcn_s_setprio(0);                                            \
    asm volatile("" ::: "memory");                                            \
    __builtin_amdgcn_s_barrier();                                             \
    _Pragma("unroll")                                                         \
    for (int m = 0; m < 4; ++m) af[m] = *(const bf16x8*)&Ab[aoff[4 + m]];     \
    if (more) gload16(bg[1] + (((k) + 3) << 5), &Bsm[wb][(tid + 512) * 8]);   \
    __builtin_amdgcn_s_barrier();                                             \
    asm volatile("s_waitcnt lgkmcnt(0)" ::: "memory");                        \
    __builtin_amdgcn_s_setprio(1);                                            \
    _Pragma("unroll")                                                         \
    for (int m = 0; m < 4; ++m)                                               \
      _Pragma("unroll")                                                       \
      for (int n = 0; n < 4; ++n)                                             \
        acc[4 + m][n] = mfma16(af[m], bf[n], acc[4 + m][n]);                  \
    __builtin_amdgcn_s_setprio(0);                                            \
    if ((k) + 2 < nt) { /* write A(k+2) from SETW into buffer (k+2)&3 */      \
      const int wbuf = ((k) + 2) & 3;                                         \
      *(bf16x8*)(al0 + wbuf * 8192) = cvt8r(W0, W1);                          \
      *(bf16x8*)(al1 + wbuf * 8192) = cvt8r(W2, W3);                          \
    }                                                                         \
    asm volatile("s_waitcnt lgkmcnt(0)" ::: "memory");                        \
    __builtin_amdgcn_s_barrier();                                             \
  }

  for (int kk = 0; kk < nt; kk += 2) {
    F32A_TILE(kk, sa0, sa1, sa2, sa3, sb0, sb1, sb2, sb3);       // even k
    F32A_TILE(kk + 1, sb0, sb1, sb2, sb3, sa0, sa1, sa2, sa3);   // odd k
  }
#undef F32A_TILE

#pragma unroll
  for (int n = 0; n < 4; ++n) {
    const size_t col = n0 + wc * 64 + n * 16 + cc;
    const float bval = bias[col];
#pragma unroll
    for (int m = 0; m < 8; ++m) {
      const size_t row0 = m0 + wr * 128 + m * 16 + cr * 4;
#pragma unroll
      for (int r = 0; r < 4; ++r) {
        const float val = acc[m][n][r] + bval;
        if constexpr (OUT == 1)
          ((ushort*)Cp)[(row0 + r) * N + col] = f2bf(val);
        else
          ((ushort*)Cp)[col * 16384 + row0 + r] = f2bf(val);
      }
    }
  }
}

// ---- windowed attention (unchanged from round 17) --------------------------

__global__ __launch_bounds__(512) void attn_kernel(
    const ushort* __restrict__ q, const ushort* __restrict__ k,
    const ushort* __restrict__ vt, ushort* __restrict__ x) {
  __shared__ __align__(16) ushort Ks[256 * 64];
  __shared__ __align__(16) ushort Vt[64 * 256];
  __shared__ ushort Pw[8][16 * 264];
  const int bid = blockIdx.x;
  const int w = bid & 15, h = (bid >> 4) & 15, b = bid >> 8;
  const int tid = threadIdx.x, lane = tid & 63, wv = tid >> 6;
  const int cc = lane & 15, cr = lane >> 4;
  const size_t base = ((size_t)b * 4096 + (size_t)w * 256) * 1024 + h * 64;
  const size_t vbase = ((size_t)h * 64) * 16384 + (size_t)b * 4096 + w * 256;

#pragma unroll
  for (int i = 0; i < 4; ++i) {
    const int u = tid + i * 512;
    const int row = u >> 3, slot = u & 7;
    gload16(k + base + (size_t)row * 1024 + ((slot ^ (row & 7)) << 3),
            &Ks[u * 8]);
  }
#pragma unroll
  for (int i = 0; i < 4; ++i) {
    const int u = tid + i * 512;
    const int dk = u >> 5, slot = u & 31;
    gload16(vt + vbase + (size_t)dk * 16384 + (((slot & 24) | ((slot ^ dk) & 7)) << 3),
            &Vt[u * 8]);
  }
  __syncthreads();

  ushort* Pp = Pw[wv];
  for (int c = 0; c < 2; ++c) {
    const int qrow0 = wv * 32 + c * 16;
    const ushort* qp = q + base + (size_t)(qrow0 + cc) * 1024 + cr * 8;
    const bf16x8 qf0 = *(const bf16x8*)qp;
    const bf16x8 qf1 = *(const bf16x8*)(qp + 32);

    f32x4 sc[16];
#pragma unroll
    for (int cb = 0; cb < 16; ++cb) {
      const int row = cb * 16 + cc;
      const bf16x8 kb0 = *(const bf16x8*)&Ks[row * 64 + ((cr ^ (row & 7)) << 3)];
      const bf16x8 kb1 =
          *(const bf16x8*)&Ks[row * 64 + (((4 + cr) ^ (row & 7)) << 3)];
      f32x4 z = {0.f, 0.f, 0.f, 0.f};
      z = mfma16(qf0, kb0, z);
      z = mfma16(qf1, kb1, z);
      sc[cb] = z;
    }

    float inv[4];
#pragma unroll
    for (int r = 0; r < 4; ++r) {
      float mx = -1e30f;
#pragma unroll
      for (int cb = 0; cb < 16; ++cb) mx = fmaxf(mx, sc[cb][r]);
      mx = fmaxf(mx, __shfl_xor(mx, 1));
      mx = fmaxf(mx, __shfl_xor(mx, 2));
      mx = fmaxf(mx, __shfl_xor(mx, 4));
      mx = fmaxf(mx, __shfl_xor(mx, 8));
      float sum = 0.f;
#pragma unroll
      for (int cb = 0; cb < 16; ++cb) {
        const float p = __expf((sc[cb][r] - mx) * 0.125f);
        sc[cb][r] = p;
        sum += p;
      }
      sum += __shfl_xor(sum, 1);
      sum += __shfl_xor(sum, 2);
      sum += __shfl_xor(sum, 4);
      sum += __shfl_xor(sum, 8);
      inv[r] = 1.f / sum;
    }

#pragma unroll
    for (int r = 0; r < 4; ++r)
#pragma unroll
      for (int cb = 0; cb < 16; ++cb)
        Pp[(cr * 4 + r) * 264 + cb * 16 + cc] = f2bf(sc[cb][r]);

    bf16x8 pf[8];
#pragma unroll
    for (int ks = 0; ks < 8; ++ks)
      pf[ks] = *(const bf16x8*)&Pp[cc * 264 + ks * 32 + cr * 8];
    f32x4 o[4] = {};
#pragma unroll
    for (int db = 0; db < 4; ++db) {
      const int row = db * 16 + cc;
#pragma unroll
      for (int ks = 0; ks < 8; ++ks) {
        const int gu = ks * 4 + cr;
        const int lu = (gu & 24) | ((gu ^ row) & 7);
        const bf16x8 bv = *(const bf16x8*)&Vt[row * 256 + lu * 8];
        o[db] = mfma16(pf[ks], bv, o[db]);
      }
    }

#pragma unroll
    for (int db = 0; db < 4; ++db)
#pragma unroll
      for (int r = 0; r < 4; ++r) {
        const int qr = qrow0 + cr * 4 + r;
        x[base + (size_t)qr * 1024 + db * 16 + cc] = f2bf(o[db][r] * inv[r]);
      }
  }
}

// ---- launch ----------------------------------------------------------------

extern "C" void kernel_launch(void* const* d_in, const int* in_sizes, int n_in,
                              void* d_out, int out_size, void* d_ws, size_t ws_size,
                              hipStream_t stream) {
  const float* query = (const float*)d_in[0];
  const float* key_  = (const float*)d_in[1];
  const float* value = (const float*)d_in[2];
  const float* Wq = (const float*)d_in[3];
  const float* bq = (const float*)d_in[4];
  const float* Wk = (const float*)d_in[5];
  const float* bk = (const float*)d_in[6];
  const float* Wv = (const float*)d_in[7];
  const float* bv = (const float*)d_in[8];
  const float* Wo = (const float*)d_in[9];
  const float* bo = (const float*)d_in[10];
  float* out = (float*)d_out;

  const size_t MN = (size_t)16384 * 1024;
  const size_t WN = (size_t)1024 * 1024;
  ushort* wqb = (ushort*)d_ws;
  ushort* wkb = wqb + WN;
  ushort* wvb = wkb + WN;
  ushort* wob = wvb + WN;
  ushort* qp = wob + WN;
  ushort* kp = qp + MN;
  ushort* vtp = kp + MN;   // V^T [1024][16384]

  const dim3 b256(256), b512(512);
  const dim3 ggrid(64 * 4);  // 256 blocks

  cvt_w<<<dim3(4 * 128), b256, 0, stream>>>(Wq, Wk, Wv, Wo, wqb, wkb, wvb, wob);

  gemm_8ph_f32a<1><<<ggrid, b512, 0, stream>>>(query, wqb, bq, qp, 1024, 1024);
  gemm_8ph_f32a<1><<<ggrid, b512, 0, stream>>>(key_,  wkb, bk, kp, 1024, 1024);
  gemm_8ph_f32a<2><<<ggrid, b512, 0, stream>>>(value, wvb, bv, vtp, 1024, 1024);

  attn_kernel<<<dim3(1024), b512, 0, stream>>>(qp, kp, vtp, qp /*in-place*/);

  gemm_8ph<0><<<ggrid, b512, 0, stream>>>(qp, wob, bo, out, 1024, 1024);
}